// Round 4
// baseline (246.122 us; speedup 1.0000x reference)
//
#include <hip/hip_runtime.h>
#include <hip/hip_bf16.h>
#include <string.h>

#define NB   2
#define SEQ  2048
#define EMB  1024
#define NH   16
#define HD   64
#define SCALE 0.03125f            // 1/sqrt(1024), folded into Q (exact pow2)
#define MADD  -3.125e18f          // -1e20 * SCALE (additive mask value)
#define KSPLIT 2

typedef __attribute__((ext_vector_type(8))) short short8;   // 8 x bf16
typedef __attribute__((ext_vector_type(4))) float f32x4;    // MFMA C/D

#define MFMA(a, b, c) __builtin_amdgcn_mfma_f32_16x16x32_bf16(a, b, c, 0, 0, 0)

__device__ __forceinline__ unsigned short f2bf(float x) {
    union { float f; unsigned u; } v; v.f = x;
    unsigned r = v.u + 0x7fffu + ((v.u >> 16) & 1u);   // RNE
    return (unsigned short)(r >> 16);
}
__device__ __forceinline__ unsigned packbf2(float a, float b) {
    __hip_bfloat162 h = __float22bfloat162_rn(make_float2(a, b));  // hw v_cvt_pk
    unsigned u; memcpy(&u, &h, 4);
    return u;
}

// ---------------------------------------------------------------------------
// Kernel 0: convert Wo/Wq/Wk/Wv fp32->bf16, build madd table.  grid 1028.
// ---------------------------------------------------------------------------
__global__ __launch_bounds__(256) void cvt_kernel(
    const float* __restrict__ Wo, const float* __restrict__ Wq,
    const float* __restrict__ Wk, const float* __restrict__ Wv,
    const int* __restrict__ mask,
    unsigned short* __restrict__ Wob, unsigned short* __restrict__ Wqb,
    unsigned short* __restrict__ Wkb, unsigned short* __restrict__ Wvb,
    float* __restrict__ maddG)
{
    const int b = blockIdx.x, tid = threadIdx.x;
    if (b < 1024) {                       // Wo: 262144 float4
        int idx = b * 256 + tid;
        float4 w = ((const float4*)Wo)[idx];
        uint2 p; p.x = packbf2(w.x, w.y); p.y = packbf2(w.z, w.w);
        ((uint2*)Wob)[idx] = p;
    } else if (b < 1027) {                // Wq/Wk/Wv: 1024 float4 each
        const float* W = (b == 1024) ? Wq : (b == 1025) ? Wk : Wv;
        unsigned short* Wb = (b == 1024) ? Wqb : (b == 1025) ? Wkb : Wvb;
        #pragma unroll
        for (int i = 0; i < 4; ++i) {
            int idx = tid + i * 256;
            float4 w = ((const float4*)W)[idx];
            uint2 p; p.x = packbf2(w.x, w.y); p.y = packbf2(w.z, w.w);
            ((uint2*)Wb)[idx] = p;
        }
    } else {                              // madd: NB*SEQ = 4096 entries
        #pragma unroll
        for (int i = 0; i < 16; ++i) {
            int idx = tid + i * 256;
            maddG[idx] = mask[idx] ? 0.f : MADD;
        }
    }
}

// ---------------------------------------------------------------------------
// Kernel 1: per-head QKV projection.  grid (SEQ/128, NH, 3*NB), block 256.
// 128 l-rows per block; W fragments straight from global bf16 (L1/L2-hot).
// Q,K out: [n][h][l][d] bf16 (Q pre-scaled by 1/32).  V out: [n][h][d][l].
// ---------------------------------------------------------------------------
__global__ __launch_bounds__(256) void qkv_kernel(
    const float* __restrict__ Qin, const float* __restrict__ Kin,
    const float* __restrict__ Vin,
    const unsigned short* __restrict__ Wqb, const unsigned short* __restrict__ Wkb,
    const unsigned short* __restrict__ Wvb, const float* __restrict__ bq,
    unsigned short* __restrict__ Qp, unsigned short* __restrict__ Kp,
    unsigned short* __restrict__ Vtp)
{
    const int lt = blockIdx.x;          // 128-row l tile
    const int h  = blockIdx.y;
    const int tz = blockIdx.z;
    const int t  = tz >> 1, n = tz & 1;

    const float* X; const unsigned short* Wb;
    if (t == 0)      { X = Qin; Wb = Wqb; }
    else if (t == 1) { X = Kin; Wb = Wkb; }
    else             { X = Vin; Wb = Wvb; }

    __shared__ __align__(16) unsigned short sX[128][70];   // pad 70: 2-way max
    __shared__ __align__(16) unsigned short sT[64][136];   // V transpose (16B rows)

    const int tid = threadIdx.x, wave = tid >> 6, lane = tid & 63;
    const int ln = lane & 15, quad = lane >> 4;

    // stage X tile (fp32 -> bf16): 2048 float4 / 256 threads = 8 each
    #pragma unroll
    for (int i = 0; i < 8; ++i) {
        int flat = tid + i * 256;
        int r = flat >> 4, c4 = flat & 15;
        float4 xv = *(const float4*)(X + ((size_t)(n * SEQ + lt * 128 + r)) * EMB + h * HD + c4 * 4);
        uint2 xp; xp.x = packbf2(xv.x, xv.y); xp.y = packbf2(xv.z, xv.w);
        *(uint2*)&sX[r][c4 * 4] = xp;
    }
    // W B-fragments from global bf16 (no LDS, no barrier dependency)
    short8 wf0[4], wf1[4];
    #pragma unroll
    for (int nt = 0; nt < 4; ++nt) {
        wf0[nt] = *(const short8*)(Wb + (nt * 16 + ln) * HD + quad * 8);
        wf1[nt] = *(const short8*)(Wb + (nt * 16 + ln) * HD + 32 + quad * 8);
    }
    __syncthreads();

    f32x4 acc[2][4];
    #pragma unroll
    for (int set = 0; set < 2; ++set) {
        short8 af0 = *(const short8*)&sX[wave * 32 + set * 16 + ln][quad * 8];
        short8 af1 = *(const short8*)&sX[wave * 32 + set * 16 + ln][32 + quad * 8];
        #pragma unroll
        for (int nt = 0; nt < 4; ++nt) {
            f32x4 a = {0.f, 0.f, 0.f, 0.f};
            a = MFMA(af0, wf0[nt], a);
            a = MFMA(af1, wf1[nt], a);
            acc[set][nt] = a;
        }
    }

    if (t == 0) {   // bias then exact pow2 scale
        #pragma unroll
        for (int nt = 0; nt < 4; ++nt) {
            float bb = bq[nt * 16 + ln];
            #pragma unroll
            for (int set = 0; set < 2; ++set)
                #pragma unroll
                for (int a = 0; a < 4; ++a)
                    acc[set][nt][a] = (acc[set][nt][a] + bb) * SCALE;
        }
    }

    if (t < 2) {
        unsigned short* Out = (t == 0) ? Qp : Kp;
        #pragma unroll
        for (int set = 0; set < 2; ++set)
            #pragma unroll
            for (int a = 0; a < 4; ++a) {
                size_t row = (size_t)((n * NH + h) * SEQ + lt * 128 + wave * 32 + set * 16 + quad * 4 + a);
                #pragma unroll
                for (int nt = 0; nt < 4; ++nt)
                    Out[row * HD + nt * 16 + ln] = f2bf(acc[set][nt][a]);
            }
    } else {
        #pragma unroll
        for (int set = 0; set < 2; ++set)
            #pragma unroll
            for (int nt = 0; nt < 4; ++nt)
                #pragma unroll
                for (int a = 0; a < 4; ++a)
                    sT[nt * 16 + ln][wave * 32 + set * 16 + quad * 4 + a] = f2bf(acc[set][nt][a]);
        __syncthreads();
        #pragma unroll
        for (int i = 0; i < 4; ++i) {
            int flat = tid + i * 256;
            int r = flat >> 4, c8 = flat & 15;
            *(float4*)(Vtp + ((size_t)((n * NH + h) * HD + r)) * SEQ + lt * 128 + c8 * 8) =
                *(const float4*)&sT[r][c8 * 8];
        }
    }
}

// ---------------------------------------------------------------------------
// Kernel 2: flash attention, S^T + sum-softmax, 2-way key split (exact:
// no online max -> O and l are plain sums; combined via fp32 atomicAdd).
// grid (NB*NH, SEQ/64, KSPLIT), block 128 (2 waves x 32 q-rows).
// ---------------------------------------------------------------------------
__global__ __launch_bounds__(128, 3) void flash_kernel(
    const unsigned short* __restrict__ Qp, const unsigned short* __restrict__ Kp,
    const unsigned short* __restrict__ Vtp, const float* __restrict__ maddG,
    float* __restrict__ Opart, float* __restrict__ lpart)
{
    const int nh = blockIdx.x;
    const int qt = blockIdx.y;
    const int z  = blockIdx.z;
    const int n  = nh >> 4;

    const int tid  = threadIdx.x;
    const int wave = tid >> 6, lane = tid & 63;
    const int ln   = lane & 15, quad = lane >> 4;

    __shared__ __align__(16) unsigned short sK [64][70];  // [key][d]   pad 70
    __shared__ __align__(16) unsigned short sVt[64][70];  // [d][key]
    __shared__ __align__(16) unsigned short sP [64][70];  // [q][key]

    // Q B-fragments (pre-scaled): q-row = qt*64 + wave*32 + set*16 + ln
    const unsigned short* Qb = Qp + ((size_t)nh * SEQ + qt * 64 + wave * 32) * HD;
    short8 qf0[2], qf1[2];
    #pragma unroll
    for (int set = 0; set < 2; ++set) {
        qf0[set] = *(const short8*)(Qb + (set * 16 + ln) * HD + quad * 8);
        qf1[set] = *(const short8*)(Qb + (set * 16 + ln) * HD + 32 + quad * 8);
    }

    const unsigned short* Kb = Kp  + (size_t)nh * SEQ * HD;
    const unsigned short* Vb = Vtp + (size_t)nh * HD * SEQ;
    const float* mb = maddG + n * SEQ;

    f32x4 o[2][4];
    #pragma unroll
    for (int s2 = 0; s2 < 2; ++s2)
        #pragma unroll
        for (int dt = 0; dt < 4; ++dt) o[s2][dt] = (f32x4){0.f, 0.f, 0.f, 0.f};
    float lsum[2] = {0.f, 0.f};

    for (int kt = z * (SEQ / 64 / KSPLIT); kt < (z + 1) * (SEQ / 64 / KSPLIT); ++kt) {
        __syncthreads();   // prev readers done
        #pragma unroll
        for (int i = 0; i < 4; ++i) {
            int flat = tid + i * 128; int r = flat >> 3, c8 = flat & 7;
            *(float4*)&sK [r][c8 * 8] = *(const float4*)(Kb + ((size_t)(kt * 64 + r)) * HD + c8 * 8);
            *(float4*)&sVt[r][c8 * 8] = *(const float4*)(Vb + (size_t)r * SEQ + kt * 64 + c8 * 8);
        }
        // mask adders for this kt (broadcast: 2 distinct addrs per instr, L1)
        float4 mdv[4];
        #pragma unroll
        for (int nt = 0; nt < 4; ++nt)
            mdv[nt] = *(const float4*)(mb + kt * 64 + nt * 16 + quad * 4);
        __syncthreads();

        // ---- S^T = K Q^T : row=key (quad*4+a), col=q (ln) ----
        f32x4 s[2][4];
        #pragma unroll
        for (int nt = 0; nt < 4; ++nt) {
            short8 kf0 = *(const short8*)&sK[nt * 16 + ln][quad * 8];
            short8 kf1 = *(const short8*)&sK[nt * 16 + ln][32 + quad * 8];
            f32x4 z0 = {0.f, 0.f, 0.f, 0.f};
            f32x4 z1 = {0.f, 0.f, 0.f, 0.f};
            z0 = MFMA(kf0, qf0[0], z0);
            z0 = MFMA(kf1, qf1[0], z0);
            z1 = MFMA(kf0, qf0[1], z1);
            z1 = MFMA(kf1, qf1[1], z1);
            s[0][nt] = z0; s[1][nt] = z1;
        }

        // ---- sum-softmax: p = exp(s + madd); P -> per-wave LDS slice ----
        #pragma unroll
        for (int set = 0; set < 2; ++set) {
            #pragma unroll
            for (int nt = 0; nt < 4; ++nt) {
                float p0 = __expf(fminf(s[set][nt][0] + mdv[nt].x, 60.f));
                float p1 = __expf(fminf(s[set][nt][1] + mdv[nt].y, 60.f));
                float p2 = __expf(fminf(s[set][nt][2] + mdv[nt].z, 60.f));
                float p3 = __expf(fminf(s[set][nt][3] + mdv[nt].w, 60.f));
                lsum[set] += (p0 + p1) + (p2 + p3);
                uint2 w; w.x = packbf2(p0, p1); w.y = packbf2(p2, p3);
                *(uint2*)&sP[wave * 32 + set * 16 + ln][nt * 16 + quad * 4] = w;
            }
        }
        asm volatile("s_waitcnt lgkmcnt(0)" ::: "memory");

        // ---- O += P V (V frags reused across both q-sets) ----
        short8 vf0[4], vf1[4];
        #pragma unroll
        for (int dt = 0; dt < 4; ++dt) {
            vf0[dt] = *(const short8*)&sVt[dt * 16 + ln][quad * 8];
            vf1[dt] = *(const short8*)&sVt[dt * 16 + ln][32 + quad * 8];
        }
        #pragma unroll
        for (int set = 0; set < 2; ++set) {
            short8 pf0 = *(const short8*)&sP[wave * 32 + set * 16 + ln][quad * 8];
            short8 pf1 = *(const short8*)&sP[wave * 32 + set * 16 + ln][32 + quad * 8];
            #pragma unroll
            for (int dt = 0; dt < 4; ++dt) {
                o[set][dt] = MFMA(pf0, vf0[dt], o[set][dt]);
                o[set][dt] = MFMA(pf1, vf1[dt], o[set][dt]);
            }
        }
    }

    // ---- epilogue: accumulate partials (exact: sum-softmax is associative) ----
    const size_t rb = (size_t)nh * SEQ + qt * 64 + wave * 32;
    #pragma unroll
    for (int set = 0; set < 2; ++set) {
        float l = lsum[set];
        l += __shfl_xor(l, 16);
        l += __shfl_xor(l, 32);
        if (quad == 0) atomicAdd(&lpart[rb + set * 16 + ln], l);
        #pragma unroll
        for (int a = 0; a < 4; ++a) {
            size_t row = rb + set * 16 + quad * 4 + a;
            #pragma unroll
            for (int dt = 0; dt < 4; ++dt)
                atomicAdd(&Opart[row * HD + dt * 16 + ln], o[set][dt][a]);
        }
    }
}

// ---------------------------------------------------------------------------
// Kernel 2b: combine partials -> normalized bf16 Aattn [n][l][EMB].
// grid 4096 x 256 (1 float4 of Opart per thread).
// ---------------------------------------------------------------------------
__global__ __launch_bounds__(256) void combine_kernel(
    const float* __restrict__ Opart, const float* __restrict__ lpart,
    unsigned short* __restrict__ Aattn)
{
    int idx = blockIdx.x * 256 + threadIdx.x;   // float4 index, 1048576 total
    int row = idx >> 4, d4 = idx & 15;          // row = (n*16+h)*2048 + l
    float4 ov = ((const float4*)Opart)[idx];
    float inv = 1.0f / lpart[row];
    int n = row >> 15, h = (row >> 11) & 15, l = row & 2047;
    uint2 p; p.x = packbf2(ov.x * inv, ov.y * inv);
    p.y = packbf2(ov.z * inv, ov.w * inv);
    *(uint2*)(Aattn + ((size_t)(n * SEQ + l)) * EMB + h * HD + d4 * 4) = p;
}

// ---------------------------------------------------------------------------
// Kernel 3: out = A @ Wo^T + bo (bf16 MFMA).  grid (EMB/64, NB*SEQ/64).
// ---------------------------------------------------------------------------
__global__ __launch_bounds__(256) void outproj_kernel(
    const unsigned short* __restrict__ A, const unsigned short* __restrict__ Wob,
    const float* __restrict__ bo, float* __restrict__ Out)
{
    const int ct = blockIdx.x;
    const int rt = blockIdx.y;

    const int tid  = threadIdx.x;
    const int wave = tid >> 6, lane = tid & 63;
    const int ln   = lane & 15, quad = lane >> 4;

    __shared__ __align__(16) unsigned short sA[64][70];
    __shared__ __align__(16) unsigned short sW[64][70];

    f32x4 acc[4];
    #pragma unroll
    for (int nt = 0; nt < 4; ++nt) acc[nt] = (f32x4){0.f, 0.f, 0.f, 0.f};

    for (int kc = 0; kc < EMB / 64; ++kc) {
        __syncthreads();
        #pragma unroll
        for (int i = 0; i < 2; ++i) {
            int flat = tid + i * 256; int r = flat >> 3, c8 = flat & 7;
            *(float4*)&sA[r][c8 * 8] =
                *(const float4*)(A + (size_t)(rt * 64 + r) * EMB + kc * 64 + c8 * 8);
            *(float4*)&sW[r][c8 * 8] =
                *(const float4*)(Wob + (size_t)(ct * 64 + r) * EMB + kc * 64 + c8 * 8);
        }
        __syncthreads();

        short8 af0 = *(const short8*)&sA[wave * 16 + ln][quad * 8];
        short8 af1 = *(const short8*)&sA[wave * 16 + ln][32 + quad * 8];
        #pragma unroll
        for (int nt = 0; nt < 4; ++nt) {
            short8 bf0 = *(const short8*)&sW[nt * 16 + ln][quad * 8];
            short8 bf1 = *(const short8*)&sW[nt * 16 + ln][32 + quad * 8];
            acc[nt] = MFMA(af0, bf0, acc[nt]);
            acc[nt] = MFMA(af1, bf1, acc[nt]);
        }
    }

    #pragma unroll
    for (int nt = 0; nt < 4; ++nt) {
        float bb = bo[ct * 64 + nt * 16 + ln];
        #pragma unroll
        for (int a = 0; a < 4; ++a) {
            size_t row = (size_t)(rt * 64 + wave * 16 + quad * 4 + a);
            Out[row * EMB + ct * 64 + nt * 16 + ln] = acc[nt][a] + bb;
        }
    }
}

// ---------------------------------------------------------------------------
extern "C" void kernel_launch(void* const* d_in, const int* in_sizes, int n_in,
                              void* d_out, int out_size, void* d_ws, size_t ws_size,
                              hipStream_t stream) {
    const float* values = (const float*)d_in[0];
    const float* key_   = (const float*)d_in[1];
    const float* query  = (const float*)d_in[2];
    const int*   mask   = (const int*)d_in[3];
    const float* Wv     = (const float*)d_in[4];
    const float* Wk     = (const float*)d_in[5];
    const float* Wq     = (const float*)d_in[6];
    const float* bq     = (const float*)d_in[7];
    const float* Wo     = (const float*)d_in[8];
    const float* bo     = (const float*)d_in[9];
    float* out = (float*)d_out;

    const size_t NHLD = (size_t)NB * NH * SEQ * HD;   // 4,194,304

    // ws layout: [Opart fp32 16MB][lpart fp32 256KB] then bf16 buffers
    float* wsf   = (float*)d_ws;
    float* Opart = wsf;                   // NHLD floats
    float* lpart = wsf + NHLD;            // 65536 floats
    unsigned short* ws2 = (unsigned short*)(wsf + NHLD + NB * NH * SEQ);
    unsigned short* Qp    = ws2;
    unsigned short* Kp    = ws2 + NHLD;
    unsigned short* Vtp   = ws2 + 2 * NHLD;
    unsigned short* Aattn = ws2 + 3 * NHLD;
    unsigned short* Wob   = ws2 + 4 * NHLD;                 // EMB*EMB
    unsigned short* Wqb   = Wob + (size_t)EMB * EMB;        // 4096 each
    unsigned short* Wkb   = Wqb + HD * HD;
    unsigned short* Wvb   = Wkb + HD * HD;
    float* maddG = (float*)(Wvb + HD * HD);                 // NB*SEQ floats

    // zero the atomic accumulation region (ws is poisoned 0xAA each launch)
    hipMemsetAsync(d_ws, 0, (NHLD + (size_t)NB * NH * SEQ) * sizeof(float), stream);

    cvt_kernel<<<dim3(1028), 256, 0, stream>>>(
        Wo, Wq, Wk, Wv, mask, Wob, Wqb, Wkb, Wvb, maddG);
    qkv_kernel<<<dim3(SEQ / 128, NH, 3 * NB), 256, 0, stream>>>(
        query, key_, values, Wqb, Wkb, Wvb, bq, Qp, Kp, Vtp);
    flash_kernel<<<dim3(NB * NH, SEQ / 64, KSPLIT), 128, 0, stream>>>(
        Qp, Kp, Vtp, maddG, Opart, lpart);
    combine_kernel<<<dim3(4096), 256, 0, stream>>>(Opart, lpart, Aattn);
    outproj_kernel<<<dim3(EMB / 64, NB * SEQ / 64), 256, 0, stream>>>(
        Aattn, Wob, bo, out);
}

// Round 5
// 210.626 us; speedup vs baseline: 1.1685x; 1.1685x over previous
//
#include <hip/hip_runtime.h>
#include <hip/hip_bf16.h>
#include <string.h>

#define NB   2
#define SEQ  2048
#define EMB  1024
#define NH   16
#define HD   64
// softmax uses exp2: fold SCALE*log2(e) into Q pre-scale and the mask table
#define QSCALE 0.045084219f       // (1/32) * log2(e)
#define MADD2  -4.5084219e18f     // -1e20 * (1/32) * log2(e)

typedef __attribute__((ext_vector_type(8))) short short8;   // 8 x bf16
typedef __attribute__((ext_vector_type(4))) float f32x4;    // MFMA C/D

#define MFMA(a, b, c) __builtin_amdgcn_mfma_f32_16x16x32_bf16(a, b, c, 0, 0, 0)
#define EXP2(x) __builtin_amdgcn_exp2f(x)

__device__ __forceinline__ unsigned short f2bf(float x) {
    union { float f; unsigned u; } v; v.f = x;
    unsigned r = v.u + 0x7fffu + ((v.u >> 16) & 1u);   // RNE
    return (unsigned short)(r >> 16);
}
__device__ __forceinline__ unsigned packbf2(float a, float b) {
    __hip_bfloat162 h = __float22bfloat162_rn(make_float2(a, b));  // hw v_cvt_pk
    unsigned u; memcpy(&u, &h, 4);
    return u;
}

// ---------------------------------------------------------------------------
// Kernel 0: convert Wo/Wq/Wk/Wv fp32->bf16, build exp2-domain madd table.
// ---------------------------------------------------------------------------
__global__ __launch_bounds__(256) void cvt_kernel(
    const float* __restrict__ Wo, const float* __restrict__ Wq,
    const float* __restrict__ Wk, const float* __restrict__ Wv,
    const int* __restrict__ mask,
    unsigned short* __restrict__ Wob, unsigned short* __restrict__ Wqb,
    unsigned short* __restrict__ Wkb, unsigned short* __restrict__ Wvb,
    float* __restrict__ maddG)
{
    const int b = blockIdx.x, tid = threadIdx.x;
    if (b < 1024) {                       // Wo: 262144 float4
        int idx = b * 256 + tid;
        float4 w = ((const float4*)Wo)[idx];
        uint2 p; p.x = packbf2(w.x, w.y); p.y = packbf2(w.z, w.w);
        ((uint2*)Wob)[idx] = p;
    } else if (b < 1027) {                // Wq/Wk/Wv: 1024 float4 each
        const float* W = (b == 1024) ? Wq : (b == 1025) ? Wk : Wv;
        unsigned short* Wb = (b == 1024) ? Wqb : (b == 1025) ? Wkb : Wvb;
        #pragma unroll
        for (int i = 0; i < 4; ++i) {
            int idx = tid + i * 256;
            float4 w = ((const float4*)W)[idx];
            uint2 p; p.x = packbf2(w.x, w.y); p.y = packbf2(w.z, w.w);
            ((uint2*)Wb)[idx] = p;
        }
    } else {                              // madd: NB*SEQ = 4096 entries
        #pragma unroll
        for (int i = 0; i < 16; ++i) {
            int idx = tid + i * 256;
            maddG[idx] = mask[idx] ? 0.f : MADD2;
        }
    }
}

// ---------------------------------------------------------------------------
// Kernel 1: per-head QKV projection.  grid (SEQ/128, NH, 3*NB), block 256.
// Q,K out: [n][h][l][d] bf16 (Q pre-scaled by QSCALE).  V out: [n][h][d][l].
// ---------------------------------------------------------------------------
__global__ __launch_bounds__(256) void qkv_kernel(
    const float* __restrict__ Qin, const float* __restrict__ Kin,
    const float* __restrict__ Vin,
    const unsigned short* __restrict__ Wqb, const unsigned short* __restrict__ Wkb,
    const unsigned short* __restrict__ Wvb, const float* __restrict__ bq,
    unsigned short* __restrict__ Qp, unsigned short* __restrict__ Kp,
    unsigned short* __restrict__ Vtp)
{
    const int lt = blockIdx.x;          // 128-row l tile
    const int h  = blockIdx.y;
    const int tz = blockIdx.z;
    const int t  = tz >> 1, n = tz & 1;

    const float* X; const unsigned short* Wb;
    if (t == 0)      { X = Qin; Wb = Wqb; }
    else if (t == 1) { X = Kin; Wb = Wkb; }
    else             { X = Vin; Wb = Wvb; }

    __shared__ __align__(16) unsigned short sX[128][70];
    __shared__ __align__(16) unsigned short sT[64][136];

    const int tid = threadIdx.x, wave = tid >> 6, lane = tid & 63;
    const int ln = lane & 15, quad = lane >> 4;

    #pragma unroll
    for (int i = 0; i < 8; ++i) {
        int flat = tid + i * 256;
        int r = flat >> 4, c4 = flat & 15;
        float4 xv = *(const float4*)(X + ((size_t)(n * SEQ + lt * 128 + r)) * EMB + h * HD + c4 * 4);
        uint2 xp; xp.x = packbf2(xv.x, xv.y); xp.y = packbf2(xv.z, xv.w);
        *(uint2*)&sX[r][c4 * 4] = xp;
    }
    short8 wf0[4], wf1[4];
    #pragma unroll
    for (int nt = 0; nt < 4; ++nt) {
        wf0[nt] = *(const short8*)(Wb + (nt * 16 + ln) * HD + quad * 8);
        wf1[nt] = *(const short8*)(Wb + (nt * 16 + ln) * HD + 32 + quad * 8);
    }
    __syncthreads();

    f32x4 acc[2][4];
    #pragma unroll
    for (int set = 0; set < 2; ++set) {
        short8 af0 = *(const short8*)&sX[wave * 32 + set * 16 + ln][quad * 8];
        short8 af1 = *(const short8*)&sX[wave * 32 + set * 16 + ln][32 + quad * 8];
        #pragma unroll
        for (int nt = 0; nt < 4; ++nt) {
            f32x4 a = {0.f, 0.f, 0.f, 0.f};
            a = MFMA(af0, wf0[nt], a);
            a = MFMA(af1, wf1[nt], a);
            acc[set][nt] = a;
        }
    }

    if (t == 0) {   // bias then fold softmax scale (incl. log2e)
        #pragma unroll
        for (int nt = 0; nt < 4; ++nt) {
            float bb = bq[nt * 16 + ln];
            #pragma unroll
            for (int set = 0; set < 2; ++set)
                #pragma unroll
                for (int a = 0; a < 4; ++a)
                    acc[set][nt][a] = (acc[set][nt][a] + bb) * QSCALE;
        }
    }

    if (t < 2) {
        unsigned short* Out = (t == 0) ? Qp : Kp;
        #pragma unroll
        for (int set = 0; set < 2; ++set)
            #pragma unroll
            for (int a = 0; a < 4; ++a) {
                size_t row = (size_t)((n * NH + h) * SEQ + lt * 128 + wave * 32 + set * 16 + quad * 4 + a);
                #pragma unroll
                for (int nt = 0; nt < 4; ++nt)
                    Out[row * HD + nt * 16 + ln] = f2bf(acc[set][nt][a]);
            }
    } else {
        #pragma unroll
        for (int set = 0; set < 2; ++set)
            #pragma unroll
            for (int nt = 0; nt < 4; ++nt)
                #pragma unroll
                for (int a = 0; a < 4; ++a)
                    sT[nt * 16 + ln][wave * 32 + set * 16 + quad * 4 + a] = f2bf(acc[set][nt][a]);
        __syncthreads();
        #pragma unroll
        for (int i = 0; i < 4; ++i) {
            int flat = tid + i * 256;
            int r = flat >> 4, c8 = flat & 15;
            *(float4*)(Vtp + ((size_t)((n * NH + h) * HD + r)) * SEQ + lt * 128 + c8 * 8) =
                *(const float4*)&sT[r][c8 * 8];
        }
    }
}

// ---------------------------------------------------------------------------
// Kernel 2: flash attention v5 — NO K-loop barriers, NO K/V LDS staging.
// K/V fragments loaded directly from global in MFMA layout (L2-hot, XCD-local
// since blockIdx.x = nh and linear%8 pins same-head blocks to one XCD).
// Each wave: 64 q-rows (4 sets) x half the keys (in-block k-split, exact
// because sum-softmax is a plain sum).  P round-trips a per-wave LDS slice.
// Final combine through LDS, bf16 Aattn written directly.
// grid (NB*NH, SEQ/64), block 128 (2 waves).
// ---------------------------------------------------------------------------
__global__ __launch_bounds__(128, 2) void flash_kernel(
    const unsigned short* __restrict__ Qp, const unsigned short* __restrict__ Kp,
    const unsigned short* __restrict__ Vtp, const float* __restrict__ maddG,
    unsigned short* __restrict__ A /* [n][l][EMB] bf16 */)
{
    const int nh = blockIdx.x;
    const int qt = blockIdx.y;
    const int n  = nh >> 4, h = nh & 15;

    const int tid  = threadIdx.x;
    const int wave = tid >> 6, lane = tid & 63;
    const int ln   = lane & 15, quad = lane >> 4;

    __shared__ __align__(16) unsigned short sP[2][64][72];   // per-wave P slices
    // epilogue exchange region overlays sP (dead after the K-loop)
    float (*xO)[65] = reinterpret_cast<float(*)[65]>(&sP[0][0][0]);
    float* xl = reinterpret_cast<float*>(reinterpret_cast<char*>(&sP[0][0][0]) + 64 * 65 * 4);

    // Q B-fragments for 4 row-sets (Q pre-scaled by QSCALE)
    const unsigned short* Qb = Qp + ((size_t)nh * SEQ + qt * 64) * HD;
    short8 qf[4][2];
    #pragma unroll
    for (int set = 0; set < 4; ++set) {
        qf[set][0] = *(const short8*)(Qb + (set * 16 + ln) * HD + quad * 8);
        qf[set][1] = *(const short8*)(Qb + (set * 16 + ln) * HD + 32 + quad * 8);
    }

    const unsigned short* Kb = Kp  + (size_t)nh * SEQ * HD;
    const unsigned short* Vb = Vtp + (size_t)nh * HD * SEQ;
    const float* mb = maddG + n * SEQ;

    f32x4 o[4][4];
    #pragma unroll
    for (int s2 = 0; s2 < 4; ++s2)
        #pragma unroll
        for (int dt = 0; dt < 4; ++dt) o[s2][dt] = (f32x4){0.f, 0.f, 0.f, 0.f};
    float lsum[4] = {0.f, 0.f, 0.f, 0.f};

    const int kt0 = wave * (SEQ / 64 / 2);          // in-block key split
    for (int kt = kt0; kt < kt0 + SEQ / 64 / 2; ++kt) {
        // V B-fragments direct from global (issued early, used after softmax)
        short8 vf[4][2];
        #pragma unroll
        for (int dt = 0; dt < 4; ++dt) {
            const unsigned short* vr = Vb + (size_t)(dt * 16 + ln) * SEQ + kt * 64;
            vf[dt][0] = *(const short8*)(vr + quad * 8);
            vf[dt][1] = *(const short8*)(vr + 32 + quad * 8);
        }

        #pragma unroll
        for (int nt = 0; nt < 4; ++nt) {
            // K A-fragments direct from global
            const unsigned short* kr = Kb + (size_t)(kt * 64 + nt * 16 + ln) * HD;
            short8 kf0 = *(const short8*)(kr + quad * 8);
            short8 kf1 = *(const short8*)(kr + 32 + quad * 8);
            float4 md  = *(const float4*)(mb + kt * 64 + nt * 16 + quad * 4);

            #pragma unroll
            for (int set = 0; set < 4; ++set) {
                f32x4 z = {0.f, 0.f, 0.f, 0.f};
                z = MFMA(kf0, qf[set][0], z);
                z = MFMA(kf1, qf[set][1], z);
                // S^T C-layout: (key = nt*16+quad*4+a, q = set*16+ln)
                float p0 = EXP2(fminf(z[0] + md.x, 80.f));
                float p1 = EXP2(fminf(z[1] + md.y, 80.f));
                float p2 = EXP2(fminf(z[2] + md.z, 80.f));
                float p3 = EXP2(fminf(z[3] + md.w, 80.f));
                lsum[set] += (p0 + p1) + (p2 + p3);
                uint2 w; w.x = packbf2(p0, p1); w.y = packbf2(p2, p3);
                *(uint2*)&sP[wave][set * 16 + ln][nt * 16 + quad * 4] = w;
            }
        }
        asm volatile("s_waitcnt lgkmcnt(0)" ::: "memory");   // per-wave slice

        // ---- O += P V ----
        #pragma unroll
        for (int set = 0; set < 4; ++set) {
            short8 pf0 = *(const short8*)&sP[wave][set * 16 + ln][quad * 8];
            short8 pf1 = *(const short8*)&sP[wave][set * 16 + ln][32 + quad * 8];
            #pragma unroll
            for (int dt = 0; dt < 4; ++dt) {
                o[set][dt] = MFMA(pf0, vf[dt][0], o[set][dt]);
                o[set][dt] = MFMA(pf1, vf[dt][1], o[set][dt]);
            }
        }
    }

    // ---- reduce l over quads (all lanes get full sum for q = set*16+ln) ----
    float lf[4];
    #pragma unroll
    for (int set = 0; set < 4; ++set) {
        float l = lsum[set];
        l += __shfl_xor(l, 16);
        l += __shfl_xor(l, 32);
        lf[set] = l;
    }

    // ---- in-block combine of the two key-halves ----
    __syncthreads();                      // both waves done with sP
    if (wave == 1) {
        #pragma unroll
        for (int set = 0; set < 4; ++set) {
            #pragma unroll
            for (int a = 0; a < 4; ++a)
                #pragma unroll
                for (int dt = 0; dt < 4; ++dt)
                    xO[set * 16 + quad * 4 + a][dt * 16 + ln] = o[set][dt][a];
            if (quad == 0) xl[set * 16 + ln] = lf[set];
        }
    }
    __syncthreads();
    if (wave == 0) {
        #pragma unroll
        for (int set = 0; set < 4; ++set)
            #pragma unroll
            for (int a = 0; a < 4; ++a) {
                int q = set * 16 + quad * 4 + a;
                float l0 = __shfl(lf[set], q & 15);        // this wave's l at q
                float inv = 1.0f / (l0 + xl[q]);
                size_t row = (size_t)(n * SEQ + qt * 64 + q);
                #pragma unroll
                for (int dt = 0; dt < 4; ++dt)
                    A[row * EMB + h * HD + dt * 16 + ln] =
                        f2bf((o[set][dt][a] + xO[q][dt * 16 + ln]) * inv);
            }
    }
}

// ---------------------------------------------------------------------------
// Kernel 3: out = A @ Wo^T + bo, 128x128 tile (m93 structure).
// grid (EMB/128, NB*SEQ/128), block 256 (2x2 waves of 64x64).
// ---------------------------------------------------------------------------
__global__ __launch_bounds__(256) void outproj_kernel(
    const unsigned short* __restrict__ A, const unsigned short* __restrict__ Wob,
    const float* __restrict__ bo, float* __restrict__ Out)
{
    const int ct = blockIdx.x;   // 128-col tile
    const int rt = blockIdx.y;   // 128-row tile

    const int tid  = threadIdx.x;
    const int wave = tid >> 6, lane = tid & 63;
    const int ln   = lane & 15, quad = lane >> 4;
    const int wm   = wave >> 1, wn = wave & 1;

    __shared__ __align__(16) unsigned short sA[128][72];
    __shared__ __align__(16) unsigned short sB[128][72];

    f32x4 acc[4][4];
    #pragma unroll
    for (int i = 0; i < 4; ++i)
        #pragma unroll
        for (int j = 0; j < 4; ++j) acc[i][j] = (f32x4){0.f, 0.f, 0.f, 0.f};

    for (int kc = 0; kc < EMB / 64; ++kc) {
        __syncthreads();
        #pragma unroll
        for (int i = 0; i < 4; ++i) {
            int flat = tid + i * 256;          // 0..1023, 8-bf16 groups
            int r = flat >> 3, c8 = flat & 7;
            *(float4*)&sA[r][c8 * 8] =
                *(const float4*)(A + (size_t)(rt * 128 + r) * EMB + kc * 64 + c8 * 8);
            *(float4*)&sB[r][c8 * 8] =
                *(const float4*)(Wob + (size_t)(ct * 128 + r) * EMB + kc * 64 + c8 * 8);
        }
        __syncthreads();

        #pragma unroll
        for (int ks = 0; ks < 2; ++ks) {
            short8 af[4], bf[4];
            #pragma unroll
            for (int i = 0; i < 4; ++i)
                af[i] = *(const short8*)&sA[wm * 64 + i * 16 + ln][ks * 32 + quad * 8];
            #pragma unroll
            for (int j = 0; j < 4; ++j)
                bf[j] = *(const short8*)&sB[wn * 64 + j * 16 + ln][ks * 32 + quad * 8];
            #pragma unroll
            for (int i = 0; i < 4; ++i)
                #pragma unroll
                for (int j = 0; j < 4; ++j)
                    acc[i][j] = MFMA(af[i], bf[j], acc[i][j]);
        }
    }

    #pragma unroll
    for (int j = 0; j < 4; ++j) {
        int col = ct * 128 + wn * 64 + j * 16 + ln;
        float bb = bo[col];
        #pragma unroll
        for (int i = 0; i < 4; ++i)
            #pragma unroll
            for (int a = 0; a < 4; ++a) {
                size_t row = (size_t)(rt * 128 + wm * 64 + i * 16 + quad * 4 + a);
                Out[row * EMB + col] = acc[i][j][a] + bb;
            }
    }
}

// ---------------------------------------------------------------------------
extern "C" void kernel_launch(void* const* d_in, const int* in_sizes, int n_in,
                              void* d_out, int out_size, void* d_ws, size_t ws_size,
                              hipStream_t stream) {
    const float* values = (const float*)d_in[0];
    const float* key_   = (const float*)d_in[1];
    const float* query  = (const float*)d_in[2];
    const int*   mask   = (const int*)d_in[3];
    const float* Wv     = (const float*)d_in[4];
    const float* Wk     = (const float*)d_in[5];
    const float* Wq     = (const float*)d_in[6];
    const float* bq     = (const float*)d_in[7];
    const float* Wo     = (const float*)d_in[8];
    const float* bo     = (const float*)d_in[9];
    float* out = (float*)d_out;

    const size_t NHLD = (size_t)NB * NH * SEQ * HD;   // 4,194,304

    unsigned short* ws = (unsigned short*)d_ws;
    unsigned short* Qp    = ws;
    unsigned short* Kp    = ws + NHLD;
    unsigned short* Vtp   = ws + 2 * NHLD;
    unsigned short* Aattn = ws + 3 * NHLD;
    unsigned short* Wob   = ws + 4 * NHLD;                  // EMB*EMB
    unsigned short* Wqb   = Wob + (size_t)EMB * EMB;
    unsigned short* Wkb   = Wqb + HD * HD;
    unsigned short* Wvb   = Wkb + HD * HD;
    float* maddG = (float*)(Wvb + HD * HD);                 // NB*SEQ floats

    cvt_kernel<<<dim3(1028), 256, 0, stream>>>(
        Wo, Wq, Wk, Wv, mask, Wob, Wqb, Wkb, Wvb, maddG);
    qkv_kernel<<<dim3(SEQ / 128, NH, 3 * NB), 256, 0, stream>>>(
        query, key_, values, Wqb, Wkb, Wvb, bq, Qp, Kp, Vtp);
    flash_kernel<<<dim3(NB * NH, SEQ / 64), 128, 0, stream>>>(
        Qp, Kp, Vtp, maddG, Aattn);
    outproj_kernel<<<dim3(EMB / 128, NB * SEQ / 128), 256, 0, stream>>>(
        Aattn, Wob, bo, out);
}